// Round 2
// baseline (330.709 us; speedup 1.0000x reference)
//
#include <hip/hip_runtime.h>
#include <math.h>

constexpr int KK = 2;
constexpr int HH = 4;
constexpr int NN = 4096;
constexpr int DD = 64;
constexpr int OO = 64;
constexpr int NU = 4000;
constexpr int CC = 2;
constexpr int JSPLIT = 4;
constexpr int JCHUNK = NN / JSPLIT;  // 1024
constexpr float LOG2E = 1.44269504088896340736f;

__device__ __forceinline__ float fexp2(float x) {
#if __has_builtin(__builtin_amdgcn_exp2f)
  return __builtin_amdgcn_exp2f(x);
#else
  return exp2f(x);
#endif
}
__device__ __forceinline__ float frcp(float x) {
#if __has_builtin(__builtin_amdgcn_rcpf)
  return __builtin_amdgcn_rcpf(x);
#else
  return 1.0f / x;
#endif
}
__device__ __forceinline__ float ftanh(float x) {
  float e = fexp2(x * (2.0f * LOG2E));
  return 1.0f - 2.0f * frcp(e + 1.0f);
}

// ---------------------------------------------------------------------------
// Phase 1: per (k,h): hp = h @ w  (4096x64 @ 64x64), then per node:
//   src'[i] = (tanh(hp_i).a_src)*log2e          -> src_s[kh][i]
//   att[k][j][h] = {(tanh(hp_j).a_dst)*log2e, hp_j.fc_w0, hp_j.fc_w1, 0}
// grid (64, K*H), block 256. Thread = 4 rows x 4 o outer-product tile.
// ---------------------------------------------------------------------------
__global__ __launch_bounds__(256) void gat_phase1(
    const float* __restrict__ hsrc, const float* __restrict__ w,
    const float* __restrict__ a_src, const float* __restrict__ a_dst,
    const float* __restrict__ fc_w,
    float* __restrict__ src_s, float4* __restrict__ att) {
  const int kh = blockIdx.y;  // 0..7
  const int k = kh >> 2;
  const int i0 = blockIdx.x * 64;
  const int tid = threadIdx.x;

  __shared__ float h_s[DD][68];  // [f][row], stride 68 -> conflict-free b128
  __shared__ float w_s[DD][OO];  // [f][o]

  {  // stage w (already [f][o] in global)
    const float4* wp = (const float4*)(w + (size_t)kh * DD * OO);
    float4* ws4 = (float4*)w_s;
    for (int t = tid; t < DD * OO / 4; t += 256) ws4[t] = wp[t];
  }
  // stage h transposed: coalesced reads (wave covers 4 rows x 1KB contiguous)
  for (int t = tid; t < 1024; t += 256) {
    const int row = t >> 4;         // 0..63
    const int f4 = (t & 15) * 4;    // 0..60
    float4 v = *(const float4*)(hsrc + (size_t)(i0 + row) * DD + f4);
    h_s[f4 + 0][row] = v.x;
    h_s[f4 + 1][row] = v.y;
    h_s[f4 + 2][row] = v.z;
    h_s[f4 + 3][row] = v.w;
  }
  __syncthreads();

  const int og = tid & 15;  // o-group (lanes 0..15 of each 16-group)
  const int rg = tid >> 4;  // row-group 0..15 (4 per wave)
  const int o0 = og * 4;
  const int r0 = rg * 4;

  float hp[4][4];
#pragma unroll
  for (int j = 0; j < 4; ++j)
#pragma unroll
    for (int u = 0; u < 4; ++u) hp[j][u] = 0.0f;

#pragma unroll 8
  for (int f = 0; f < DD; ++f) {
    float4 hv = *(const float4*)&h_s[f][r0];
    float4 wv = *(const float4*)&w_s[f][o0];
    hp[0][0] = fmaf(hv.x, wv.x, hp[0][0]);
    hp[0][1] = fmaf(hv.x, wv.y, hp[0][1]);
    hp[0][2] = fmaf(hv.x, wv.z, hp[0][2]);
    hp[0][3] = fmaf(hv.x, wv.w, hp[0][3]);
    hp[1][0] = fmaf(hv.y, wv.x, hp[1][0]);
    hp[1][1] = fmaf(hv.y, wv.y, hp[1][1]);
    hp[1][2] = fmaf(hv.y, wv.z, hp[1][2]);
    hp[1][3] = fmaf(hv.y, wv.w, hp[1][3]);
    hp[2][0] = fmaf(hv.z, wv.x, hp[2][0]);
    hp[2][1] = fmaf(hv.z, wv.y, hp[2][1]);
    hp[2][2] = fmaf(hv.z, wv.z, hp[2][2]);
    hp[2][3] = fmaf(hv.z, wv.w, hp[2][3]);
    hp[3][0] = fmaf(hv.w, wv.x, hp[3][0]);
    hp[3][1] = fmaf(hv.w, wv.y, hp[3][1]);
    hp[3][2] = fmaf(hv.w, wv.z, hp[3][2]);
    hp[3][3] = fmaf(hv.w, wv.w, hp[3][3]);
  }

  // per-thread o-slice of the epilogue vectors
  float as[4], ad[4], f0[4], f1[4];
#pragma unroll
  for (int u = 0; u < 4; ++u) {
    as[u] = a_src[kh * OO + o0 + u];
    ad[u] = a_dst[kh * OO + o0 + u];
    f0[u] = fc_w[0 * (KK * OO) + k * OO + o0 + u];
    f1[u] = fc_w[1 * (KK * OO) + k * OO + o0 + u];
  }

#pragma unroll
  for (int j = 0; j < 4; ++j) {
    float sp = 0.0f, dp = 0.0f, g0 = 0.0f, g1 = 0.0f;
#pragma unroll
    for (int u = 0; u < 4; ++u) {
      float v = hp[j][u];
      float t = ftanh(v);
      sp = fmaf(t, as[u], sp);
      dp = fmaf(t, ad[u], dp);
      g0 = fmaf(v, f0[u], g0);
      g1 = fmaf(v, f1[u], g1);
    }
    // reduce across the 16 o-groups (lane bits 0..3)
#pragma unroll
    for (int off = 1; off < 16; off <<= 1) {
      sp += __shfl_xor(sp, off, 64);
      dp += __shfl_xor(dp, off, 64);
      g0 += __shfl_xor(g0, off, 64);
      g1 += __shfl_xor(g1, off, 64);
    }
    if (og == 0) {
      const int i = i0 + r0 + j;
      src_s[kh * NN + i] = sp * LOG2E;
      // att layout: [k][j][h]
      att[((size_t)k * NN + i) * HH + (kh & 3)] =
          make_float4(dp * LOG2E, g0, g1, 0.0f);
    }
  }
}

// ---------------------------------------------------------------------------
// Phase 2: partial softmax sums over a j-chunk.
// grid (NU/8, K*JSPLIT), block 256 = 4 waves; wave w owns rows i0+2w, i0+2w+1.
// Lane covers 4 consecutive j (one float4 of adj). Per (row, head):
//   p = adj * exp2(leaky(src'+dst')); l += p; a_c += p*g_c
// Wave butterfly-reduces its 24 sums, lane0 writes partials (no division).
// ---------------------------------------------------------------------------
__global__ __launch_bounds__(256) void gat_phase2(
    const float* __restrict__ adj, const float* __restrict__ src_s,
    const float4* __restrict__ att, float* __restrict__ P) {
  const int k = blockIdx.y >> 2;
  const int chunk = blockIdx.y & 3;
  const int i0 = blockIdx.x * 8;
  const int tid = threadIdx.x;
  const int wv = tid >> 6;
  const int lane = tid & 63;
  const int r0 = i0 + wv * 2;

  float srcv[2][4];
#pragma unroll
  for (int r = 0; r < 2; ++r)
#pragma unroll
    for (int q = 0; q < 4; ++q)
      srcv[r][q] = src_s[(k * HH + q) * NN + r0 + r];

  float lacc[2][4];
  float cacc[2][4][2];
#pragma unroll
  for (int r = 0; r < 2; ++r)
#pragma unroll
    for (int q = 0; q < 4; ++q) {
      lacc[r][q] = 0.0f;
      cacc[r][q][0] = 0.0f;
      cacc[r][q][1] = 0.0f;
    }

  const float* adjk = adj + (size_t)k * NN * NN;
  const float4* attk = att + (size_t)k * NN * HH;
  const int jb0 = chunk * JCHUNK + lane * 4;

#pragma unroll 2
  for (int it = 0; it < JCHUNK / 256; ++it) {  // 4 iterations
    const int jb = jb0 + it * 256;
    float4 ar0 = *(const float4*)(adjk + (size_t)(r0 + 0) * NN + jb);
    float4 ar1 = *(const float4*)(adjk + (size_t)(r0 + 1) * NN + jb);
    float e0[4] = {ar0.x, ar0.y, ar0.z, ar0.w};
    float e1[4] = {ar1.x, ar1.y, ar1.z, ar1.w};
    const float4* attb = attk + (size_t)jb * HH;
#pragma unroll
    for (int jj = 0; jj < 4; ++jj) {
      float4 av[4];
      av[0] = attb[jj * HH + 0];
      av[1] = attb[jj * HH + 1];
      av[2] = attb[jj * HH + 2];
      av[3] = attb[jj * HH + 3];
#pragma unroll
      for (int q = 0; q < 4; ++q) {
        const float d = av[q].x, g0 = av[q].y, g1 = av[q].z;
        {
          float s = srcv[0][q] + d;
          float sl = fmaxf(s, 0.2f * s);
          float p = e0[jj] * fexp2(sl);
          lacc[0][q] += p;
          cacc[0][q][0] = fmaf(p, g0, cacc[0][q][0]);
          cacc[0][q][1] = fmaf(p, g1, cacc[0][q][1]);
        }
        {
          float s = srcv[1][q] + d;
          float sl = fmaxf(s, 0.2f * s);
          float p = e1[jj] * fexp2(sl);
          lacc[1][q] += p;
          cacc[1][q][0] = fmaf(p, g0, cacc[1][q][0]);
          cacc[1][q][1] = fmaf(p, g1, cacc[1][q][1]);
        }
      }
    }
  }

  // butterfly reduce the 24 accumulators across 64 lanes
#pragma unroll
  for (int r = 0; r < 2; ++r)
#pragma unroll
    for (int q = 0; q < 4; ++q) {
      float x0 = lacc[r][q], x1 = cacc[r][q][0], x2 = cacc[r][q][1];
#pragma unroll
      for (int off = 32; off > 0; off >>= 1) {
        x0 += __shfl_xor(x0, off, 64);
        x1 += __shfl_xor(x1, off, 64);
        x2 += __shfl_xor(x2, off, 64);
      }
      lacc[r][q] = x0;
      cacc[r][q][0] = x1;
      cacc[r][q][1] = x2;
    }

  if (lane == 0) {
#pragma unroll
    for (int r = 0; r < 2; ++r)
#pragma unroll
      for (int q = 0; q < 4; ++q) {
        // P layout: [k][chunk][q][{l,a0,a1}][i]  (i fastest -> phase3 coalesced)
        size_t base =
            (((size_t)(k * JSPLIT + chunk) * HH + q) * 3) * NU + (r0 + r);
        P[base] = lacc[r][q];
        P[base + NU] = cacc[r][q][0];
        P[base + 2 * (size_t)NU] = cacc[r][q][1];
      }
  }
}

// ---------------------------------------------------------------------------
// Phase 3: combine chunk partials, divide, mean heads, sum kinds, +bias,
// log_softmax over C=2.
// ---------------------------------------------------------------------------
__global__ __launch_bounds__(256) void gat_phase3(
    const float* __restrict__ P, const float* __restrict__ fc_b,
    float* __restrict__ out) {
  const int i = blockIdx.x * 256 + threadIdx.x;
  if (i >= NU) return;
  float l0 = fc_b[0], l1 = fc_b[1];
#pragma unroll
  for (int k = 0; k < KK; ++k) {
#pragma unroll
    for (int q = 0; q < HH; ++q) {
      float ls = 0.0f, a0 = 0.0f, a1 = 0.0f;
#pragma unroll
      for (int ch = 0; ch < JSPLIT; ++ch) {
        size_t b = (((size_t)(k * JSPLIT + ch) * HH + q) * 3) * NU + i;
        ls += P[b];
        a0 += P[b + NU];
        a1 += P[b + 2 * (size_t)NU];
      }
      float inv = 1.0f / ls;
      l0 = fmaf(0.25f * a0, inv, l0);
      l1 = fmaf(0.25f * a1, inv, l1);
    }
  }
  float m = fmaxf(l0, l1);
  float lse = m + logf(expf(l0 - m) + expf(l1 - m));
  out[i * CC + 0] = l0 - lse;
  out[i * CC + 1] = l1 - lse;
}

extern "C" void kernel_launch(void* const* d_in, const int* in_sizes, int n_in,
                              void* d_out, int out_size, void* d_ws, size_t ws_size,
                              hipStream_t stream) {
  const float* hsrc  = (const float*)d_in[0];  // (1,4096,64)
  const float* hadj  = (const float*)d_in[1];  // (2,1,4096,4096)
  const float* w     = (const float*)d_in[2];  // (2,4,64,64)
  const float* a_src = (const float*)d_in[3];  // (2,4,64,1)
  const float* a_dst = (const float*)d_in[4];  // (2,4,64,1)
  const float* fc_w  = (const float*)d_in[5];  // (2,128)
  const float* fc_b  = (const float*)d_in[6];  // (2,)
  float* out = (float*)d_out;                  // (1,4000,2) fp32

  char* ws = (char*)d_ws;
  float*  src_s = (float*)ws;                        // K*H*N floats (128 KB)
  float4* att   = (float4*)(ws + 131072);            // K*N*H float4 (512 KB)
  float*  P     = (float*)(ws + 131072 + 524288);    // K*JSPLIT*H*3*NU (1.5 MB)

  dim3 g1(NN / 64, KK * HH);
  gat_phase1<<<g1, 256, 0, stream>>>(hsrc, w, a_src, a_dst, fc_w, src_s, att);
  dim3 g2(NU / 8, KK * JSPLIT);
  gat_phase2<<<g2, 256, 0, stream>>>(hadj, src_s, att, P);
  gat_phase3<<<(NU + 255) / 256, 256, 0, stream>>>(P, fc_b, out);
}